// Round 2
// baseline (768.316 us; speedup 1.0000x reference)
//
#include <hip/hip_runtime.h>

typedef _Float16 f16;
typedef _Float16 f16x8 __attribute__((ext_vector_type(8)));
typedef _Float16 f16x4 __attribute__((ext_vector_type(4)));
typedef float f32x4 __attribute__((ext_vector_type(4)));

#define TD 512
#define TDH 2048

__device__ __forceinline__ float gelu_exact(float v) {
  return 0.5f * v * (1.0f + erff(v * 0.7071067811865475f));
}

__device__ __forceinline__ void glds16(const void* g, void* l) {
  __builtin_amdgcn_global_load_lds(
      (const __attribute__((address_space(1))) void*)g,
      (__attribute__((address_space(3))) void*)l, 16, 0, 0);
}

__global__ __launch_bounds__(256) void k_conv_x(f16* __restrict__ dst,
                                                const float* __restrict__ src,
                                                int n4) {
  int i = blockIdx.x * 256 + threadIdx.x;
  if (i >= n4) return;
  float4 v = ((const float4*)src)[i];
  f16x4 o = {(f16)v.x, (f16)v.y, (f16)v.z, (f16)v.w};
  ((f16x4*)dst)[i] = o;
}

// dst[c*R + r] = src[r*C + c]  (dst has C*R elems)
__global__ __launch_bounds__(256) void k_trans(f16* __restrict__ dst,
                                               const float* __restrict__ src,
                                               int R, int C) {
  int i = blockIdx.x * 256 + threadIdx.x;
  if (i >= R * C) return;
  int c = i / R, r = i - c * R;
  dst[i] = (f16)src[(size_t)r * C + c];
}

// wdT[128][512]: n=e*8+r for n<24 else 0 ; src wd[3][512][8]
__global__ __launch_bounds__(256) void k_wdT(f16* __restrict__ dst,
                                             const float* __restrict__ wd) {
  int i = blockIdx.x * 256 + threadIdx.x;  // 65536 total
  int n = i >> 9, k = i & 511;
  float v = (n < 24) ? wd[(size_t)((n >> 3) * 512 + k) * 8 + (n & 7)] : 0.0f;
  dst[i] = (f16)v;
}

// wuT[512][32]: wuT[d][e*8+r] = wu[e][r][d] for er<24 else 0 ; src wu[3][8][512]
__global__ __launch_bounds__(256) void k_wuT(f16* __restrict__ dst,
                                             const float* __restrict__ wu) {
  int i = blockIdx.x * 256 + threadIdx.x;  // 16384 total
  int d = i >> 5, er = i & 31;
  float v = (er < 24) ? wu[(size_t)(er >> 3) * 4096 + (er & 7) * 512 + d] : 0.0f;
  dst[i] = (f16)v;
}

// 128x128 tile, BK=32, 4 waves (2x2), each wave 64x64 = 4x4 frags of 16x16x32.
// A: [M][K] row-major (K-contig). B: B^T layout [N][K] (K-contig).
// EPI 0: Hout = f16(gelu(acc + bias[col]))          (ldh)
// EPI 1: Out[row*ldc+col] += acc
// EPI 2: g:  Hout[row*32+col] = f16(topk_w(row, col>>3) * gelu(acc)), cols 0..31
// EPI 3: Out[row*ldc+col] = acc + bias[col]
template <int EPI>
__global__ __launch_bounds__(256) void k_gemm(
    const f16* __restrict__ A, const f16* __restrict__ B, int Kt, int lda,
    int ldb, const float* __restrict__ bias, f16* __restrict__ Hout, int ldh,
    float* __restrict__ Out, int ldc, const float* __restrict__ tkp,
    const int* __restrict__ tki) {
  __shared__ __align__(16) f16 As[128 * 32];
  __shared__ __align__(16) f16 Bs[128 * 32];
  const int tid = threadIdx.x;
  const int lane = tid & 63;
  const int w = tid >> 6;
  const int wm = w >> 1, wn = w & 1;
  const int bm = blockIdx.x, bn = blockIdx.y;

  // staging: wave w fills chunks 2w, 2w+1 of each 8KB tile.
  // chunk c covers rows c*16..c*16+15 (64B per row); lane l -> row c*16+l/4,
  // k = (l&3)*8  (16B per lane, LDS dest = wave-uniform base + lane*16).
  const int c0 = 2 * w;
  const int srow = c0 * 16 + (lane >> 2);
  const int skk = (lane & 3) * 8;
  const f16* gA0 = A + (size_t)(bm * 128 + srow) * lda + skk;
  const f16* gA1 = gA0 + (size_t)16 * lda;
  const f16* gB0 = B + (size_t)(bn * 128 + srow) * ldb + skk;
  const f16* gB1 = gB0 + (size_t)16 * ldb;
  f16* lA0 = &As[c0 * 512];
  f16* lB0 = &Bs[c0 * 512];

  f32x4 acc[4][4] = {};

  const int frow = lane & 15;
  const int fk = (lane >> 4) * 8;

  for (int k0 = 0; k0 < Kt; k0 += 32) {
    glds16(gA0 + k0, lA0);
    glds16(gA1 + k0, lA0 + 512);
    glds16(gB0 + k0, lB0);
    glds16(gB1 + k0, lB0 + 512);
    __syncthreads();  // drains vmcnt -> LDS tiles ready
    f16x8 af[4], bf[4];
#pragma unroll
    for (int i = 0; i < 4; i++)
      af[i] = *(const f16x8*)&As[(wm * 64 + i * 16 + frow) * 32 + fk];
#pragma unroll
    for (int j = 0; j < 4; j++)
      bf[j] = *(const f16x8*)&Bs[(wn * 64 + j * 16 + frow) * 32 + fk];
#pragma unroll
    for (int i = 0; i < 4; i++)
#pragma unroll
      for (int j = 0; j < 4; j++)
        acc[i][j] = __builtin_amdgcn_mfma_f32_16x16x32_f16(af[i], bf[j],
                                                           acc[i][j], 0, 0, 0);
    __syncthreads();
  }

  // C/D layout (verified m89/m91): col = lane&15, row = (lane>>4)*4 + reg
  const int rbase = bm * 128 + wm * 64 + (lane >> 4) * 4;
  const int cbase = bn * 128 + wn * 64 + (lane & 15);

  if constexpr (EPI == 0) {
#pragma unroll
    for (int i = 0; i < 4; i++)
#pragma unroll
      for (int j = 0; j < 4; j++) {
        const int col = cbase + j * 16;
        const float bb = bias[col];
#pragma unroll
        for (int r = 0; r < 4; r++) {
          const int row = rbase + i * 16 + r;
          Hout[(size_t)row * ldh + col] = (f16)gelu_exact(acc[i][j][r] + bb);
        }
      }
  } else if constexpr (EPI == 1) {
#pragma unroll
    for (int i = 0; i < 4; i++)
#pragma unroll
      for (int j = 0; j < 4; j++) {
        const int col = cbase + j * 16;
#pragma unroll
        for (int r = 0; r < 4; r++) {
          const int row = rbase + i * 16 + r;
          Out[(size_t)row * ldc + col] += acc[i][j][r];
        }
      }
  } else if constexpr (EPI == 2) {
    if (wn == 1) return;  // only cols 0..31 carry data (after final barrier)
#pragma unroll
    for (int i = 0; i < 4; i++)
#pragma unroll
      for (int j = 0; j < 2; j++) {
        const int col = (lane & 15) + j * 16;  // 0..31
        const int e = col >> 3;                // 0..3 (e==3 -> weight 0)
#pragma unroll
        for (int r = 0; r < 4; r++) {
          const int row = rbase + i * 16 + r;
          const int i0 = tki[row * 2], i1 = tki[row * 2 + 1];
          const float p0 = tkp[row * 2], p1 = tkp[row * 2 + 1];
          const float wgt = (i0 == e ? p0 : 0.0f) + (i1 == e ? p1 : 0.0f);
          Hout[(size_t)row * 32 + col] = (f16)(wgt * gelu_exact(acc[i][j][r]));
        }
      }
  } else {  // EPI == 3
#pragma unroll
    for (int i = 0; i < 4; i++)
#pragma unroll
      for (int j = 0; j < 4; j++) {
        const int col = cbase + j * 16;
        const float bb = bias[col];
#pragma unroll
        for (int r = 0; r < 4; r++) {
          const int row = rbase + i * 16 + r;
          Out[(size_t)row * ldc + col] = acc[i][j][r] + bb;
        }
      }
  }
}

extern "C" void kernel_launch(void* const* d_in, const int* in_sizes, int n_in,
                              void* d_out, int out_size, void* d_ws,
                              size_t ws_size, hipStream_t stream) {
  const float* x = (const float*)d_in[0];
  const float* W1 = (const float*)d_in[1];
  const float* b1 = (const float*)d_in[2];
  const float* W2 = (const float*)d_in[3];
  const float* b2 = (const float*)d_in[4];
  const float* wd = (const float*)d_in[5];
  const float* wu = (const float*)d_in[6];
  // d_in[7] = gate_probs (unused; topk already provided)
  const float* tkp = (const float*)d_in[8];
  const int* tki = (const int*)d_in[9];
  float* out = (float*)d_out;

  const int T = in_sizes[0] / TD;  // 50176

  // workspace layout
  char* p = (char*)d_ws;
  f16* W1T = (f16*)p; p += (size_t)TDH * TD * sizeof(f16);  // [2048][512]
  f16* W2T = (f16*)p; p += (size_t)TD * TDH * sizeof(f16);  // [512][2048]
  f16* wdT = (f16*)p; p += (size_t)128 * TD * sizeof(f16);  // [128][512]
  f16* wuT = (f16*)p; p += (size_t)TD * 32 * sizeof(f16);   // [512][32]
  size_t fixed = (size_t)(p - (char*)d_ws);
  const size_t per_tok = (size_t)(TD + TDH + 32) * sizeof(f16);  // 5184 B
  long mc = (long)((ws_size > fixed ? ws_size - fixed : 0) / per_tok);
  if (mc > T) mc = T;
  mc = (mc / 128) * 128;
  if (mc < 128) mc = 128;  // minimum viable chunk
  f16* xb = (f16*)p; p += (size_t)mc * TD * sizeof(f16);
  f16* Hb = (f16*)p; p += (size_t)mc * TDH * sizeof(f16);
  f16* gb = (f16*)p;

  // one-time weight conversion/transpose (runs every call; ~8 MB cached reads)
  k_trans<<<dim3((TD * TDH + 255) / 256), 256, 0, stream>>>(W1T, W1, TD, TDH);
  k_trans<<<dim3((TD * TDH + 255) / 256), 256, 0, stream>>>(W2T, W2, TDH, TD);
  k_wdT<<<dim3(65536 / 256), 256, 0, stream>>>(wdT, wd);
  k_wuT<<<dim3(16384 / 256), 256, 0, stream>>>(wuT, wu);

  for (long off = 0; off < T; off += mc) {
    long m = T - off;
    if (m > mc) m = mc;
    const int mt = (int)(m / 128);
    const int n4 = (int)(m * TD / 4);
    k_conv_x<<<dim3((n4 + 255) / 256), 256, 0, stream>>>(xb, x + off * TD, n4);
    // g[m][32] = weighted gelu(x @ wd^T)   (K=512, N=128 padded, keep 32 cols)
    k_gemm<2><<<dim3(mt, 1), 256, 0, stream>>>(xb, wdT, TD, TD, TD, nullptr,
                                               gb, 32, nullptr, 0,
                                               tkp + off * 2, tki + off * 2);
    // out = g @ wu^T + b2   (K=32, N=512) — initializes every output element
    k_gemm<3><<<dim3(mt, TD / 128), 256, 0, stream>>>(
        gb, wuT, 32, 32, 32, b2, nullptr, 0, out + off * TD, TD, nullptr,
        nullptr);
    // H = gelu(x @ W1^T + b1)   (K=512, N=2048)
    k_gemm<0><<<dim3(mt, TDH / 128), 256, 0, stream>>>(
        xb, W1T, TD, TD, TD, b1, Hb, TDH, nullptr, 0, nullptr, nullptr);
    // out += H @ W2^T   (K=2048, N=512)
    k_gemm<1><<<dim3(mt, TD / 128), 256, 0, stream>>>(
        Hb, W2T, TDH, TDH, TDH, nullptr, nullptr, 0, out + off * TD, TD,
        nullptr, nullptr);
  }
}

// Round 3
// 611.893 us; speedup vs baseline: 1.2556x; 1.2556x over previous
//
#include <hip/hip_runtime.h>

typedef _Float16 f16;
typedef _Float16 f16x8 __attribute__((ext_vector_type(8)));
typedef _Float16 f16x4 __attribute__((ext_vector_type(4)));
typedef float f32x4 __attribute__((ext_vector_type(4)));

#define TD 512
#define TDH 2048

__device__ __forceinline__ float gelu_exact(float v) {
  return 0.5f * v * (1.0f + erff(v * 0.7071067811865475f));
}

__device__ __forceinline__ void glds16(const f16* g, f16* l) {
  __builtin_amdgcn_global_load_lds(
      (const __attribute__((address_space(1))) void*)g,
      (__attribute__((address_space(3))) void*)l, 16, 0, 0);
}

__global__ __launch_bounds__(256) void k_conv_x(f16* __restrict__ dst,
                                                const float* __restrict__ src,
                                                int n4) {
  int i = blockIdx.x * 256 + threadIdx.x;
  if (i >= n4) return;
  float4 v = ((const float4*)src)[i];
  f16x4 o = {(f16)v.x, (f16)v.y, (f16)v.z, (f16)v.w};
  ((f16x4*)dst)[i] = o;
}

// Tiled transpose: dst[c*R + r] = src[r*C + c], both sides coalesced.
// grid (C/32, R/32), block (32, 8).
__global__ void k_trans(f16* __restrict__ dst, const float* __restrict__ src,
                        int R, int C) {
  __shared__ float t[32][33];
  const int bx = blockIdx.x, by = blockIdx.y;
  const int tx = threadIdx.x, ty = threadIdx.y;
#pragma unroll
  for (int s = 0; s < 32; s += 8)
    t[ty + s][tx] = src[(size_t)(by * 32 + ty + s) * C + bx * 32 + tx];
  __syncthreads();
#pragma unroll
  for (int s = 0; s < 32; s += 8)
    dst[(size_t)(bx * 32 + ty + s) * R + by * 32 + tx] = (f16)t[tx][ty + s];
}

// wdT[128][512]: n=e*8+r for n<24 else 0 ; src wd[3][512][8]
__global__ __launch_bounds__(256) void k_wdT(f16* __restrict__ dst,
                                             const float* __restrict__ wd) {
  int i = blockIdx.x * 256 + threadIdx.x;  // 65536 total
  int n = i >> 9, k = i & 511;
  float v = (n < 24) ? wd[(size_t)((n >> 3) * 512 + k) * 8 + (n & 7)] : 0.0f;
  dst[i] = (f16)v;
}

// wuT[512][32]: wuT[d][e*8+r] = wu[e][r][d] for er<24 else 0 ; src wu[3][8][512]
__global__ __launch_bounds__(256) void k_wuT(f16* __restrict__ dst,
                                             const float* __restrict__ wu) {
  int i = blockIdx.x * 256 + threadIdx.x;  // 16384 total
  int d = i >> 5, er = i & 31;
  float v = (er < 24) ? wu[(size_t)(er >> 3) * 4096 + (er & 7) * 512 + d] : 0.0f;
  dst[i] = (f16)v;
}

// 128x128 tile, BK=32, 4 waves (2x2), double-buffered LDS, early-issue STAGE.
// A: [M][K] K-contig. B: B^T layout [N][K] K-contig.
// MFMA called as mfma(bf, af) so D reg axis = N (4 consecutive cols/thread)
// -> vectorized epilogue stores.
// EPI 0: Hout[m][n] = f16(gelu(acc + bias[n]))
// EPI 1: Out[m][n]  = acc(main K over A/B  PLUS one fused K=32 step Ag@Bg) + bias[n]
// EPI 2: Hout[m*32+n] = f16(topk_w(m, n>>3) * gelu(acc)), n<32
template <int EPI>
__global__ __launch_bounds__(256) void k_gemm(
    const f16* __restrict__ A, const f16* __restrict__ B, int Kt, int lda,
    int ldb, const float* __restrict__ bias, f16* __restrict__ Hout, int ldh,
    float* __restrict__ Out, int ldc, const float* __restrict__ tkp,
    const int* __restrict__ tki, const f16* __restrict__ Ag,
    const f16* __restrict__ Bg) {
  __shared__ __align__(16) f16 As[2][128 * 32];
  __shared__ __align__(16) f16 Bs[2][128 * 32];
  const int tid = threadIdx.x;
  const int lane = tid & 63;
  const int w = tid >> 6;
  const int wm = w >> 1, wn = w & 1;
  const int bm = blockIdx.x, bn = blockIdx.y;

  // Staging: wave w fills chunks 2w,2w+1 (16 rows x 64B each). LDS dest is
  // wave-linear (lane l -> row c*16+l/4, 16B slot l&3). Source slot is
  // XOR-swizzled (m173 both-sides pattern): LDS[row][s] = glob[row][s^(row&3)]
  const int c0 = 2 * w;
  const int lrow = lane >> 2;
  const int srow = c0 * 16 + lrow;
  const int skk = ((lane & 3) ^ (lrow & 3)) * 8;
  const f16* gA = A + (size_t)(bm * 128 + srow) * lda + skk;
  const f16* gB = B + (size_t)(bn * 128 + srow) * ldb + skk;
  f16* lA0 = &As[0][c0 * 512];
  f16* lA1 = &As[1][c0 * 512];
  f16* lB0 = &Bs[0][c0 * 512];
  f16* lB1 = &Bs[1][c0 * 512];

  f32x4 acc[4][4] = {};

  const int frow = lane & 15;
  // read-side swizzle: slot' = (lane>>4) ^ (row&3); row&3 == frow&3 always
  const int swk = (((lane >> 4) ^ (frow & 3))) * 8;

  const int nt = Kt / 32;

  // prologue: stage k=0 into buf0
  glds16(gA, lA0);
  glds16(gA + (size_t)16 * lda, lA0 + 512);
  glds16(gB, lB0);
  glds16(gB + (size_t)16 * ldb, lB0 + 512);
  __syncthreads();

  for (int t = 0; t < nt; ++t) {
    // issue next-tile stage FIRST (loads fly under ds_read + MFMA)
    f16* dA = (t & 1) ? lA0 : lA1;
    f16* dB = (t & 1) ? lB0 : lB1;
    if (t + 1 < nt) {
      const int k = (t + 1) * 32;
      glds16(gA + k, dA);
      glds16(gA + k + (size_t)16 * lda, dA + 512);
      glds16(gB + k, dB);
      glds16(gB + k + (size_t)16 * ldb, dB + 512);
    } else if (EPI == 1) {  // fused LoRA-up step: A=Ag[m][32], B=Bg[n][32]
      const f16* gAg = Ag + (size_t)(bm * 128 + srow) * 32 + skk;
      const f16* gBg = Bg + (size_t)(bn * 128 + srow) * 32 + skk;
      glds16(gAg, dA);
      glds16(gAg + 512, dA + 512);
      glds16(gBg, dB);
      glds16(gBg + 512, dB + 512);
    }
    const f16* rA = As[t & 1];
    const f16* rB = Bs[t & 1];
    f16x8 af[4], bf[4];
#pragma unroll
    for (int i = 0; i < 4; i++)
      af[i] = *(const f16x8*)&rA[(wm * 64 + i * 16 + frow) * 32 + swk];
#pragma unroll
    for (int j = 0; j < 4; j++)
      bf[j] = *(const f16x8*)&rB[(wn * 64 + j * 16 + frow) * 32 + swk];
#pragma unroll
    for (int i = 0; i < 4; i++)
#pragma unroll
      for (int j = 0; j < 4; j++)
        acc[i][j] = __builtin_amdgcn_mfma_f32_16x16x32_f16(bf[j], af[i],
                                                           acc[i][j], 0, 0, 0);
    __syncthreads();  // vmcnt(0): next buf staged; lgkm: reads done before overwrite
  }

  if constexpr (EPI == 1) {  // consume the fused g @ wuT tile
    const f16* rA = As[nt & 1];
    const f16* rB = Bs[nt & 1];
    f16x8 af[4], bf[4];
#pragma unroll
    for (int i = 0; i < 4; i++)
      af[i] = *(const f16x8*)&rA[(wm * 64 + i * 16 + frow) * 32 + swk];
#pragma unroll
    for (int j = 0; j < 4; j++)
      bf[j] = *(const f16x8*)&rB[(wn * 64 + j * 16 + frow) * 32 + swk];
#pragma unroll
    for (int i = 0; i < 4; i++)
#pragma unroll
      for (int j = 0; j < 4; j++)
        acc[i][j] = __builtin_amdgcn_mfma_f32_16x16x32_f16(bf[j], af[i],
                                                           acc[i][j], 0, 0, 0);
  }

  // D layout with swapped operands: col(lane&15) -> m, reg axis -> n.
  // m = wm*64 + i*16 + (lane&15); n = wn*64 + j*16 + (lane>>4)*4 + r
  const int m0 = wm * 64 + (lane & 15);
  const int n0 = wn * 64 + ((lane >> 4) << 2);

  if constexpr (EPI == 0) {
#pragma unroll
    for (int i = 0; i < 4; i++) {
      const size_t rb = (size_t)(bm * 128 + m0 + i * 16) * ldh + bn * 128 + n0;
#pragma unroll
      for (int j = 0; j < 4; j++) {
        const float4 bb = *(const float4*)&bias[bn * 128 + n0 + j * 16];
        f16x4 o = {(f16)gelu_exact(acc[i][j][0] + bb.x),
                   (f16)gelu_exact(acc[i][j][1] + bb.y),
                   (f16)gelu_exact(acc[i][j][2] + bb.z),
                   (f16)gelu_exact(acc[i][j][3] + bb.w)};
        *(f16x4*)&Hout[rb + j * 16] = o;
      }
    }
  } else if constexpr (EPI == 1) {
#pragma unroll
    for (int i = 0; i < 4; i++) {
      const size_t rb = (size_t)(bm * 128 + m0 + i * 16) * ldc + bn * 128 + n0;
#pragma unroll
      for (int j = 0; j < 4; j++) {
        const float4 bb = *(const float4*)&bias[bn * 128 + n0 + j * 16];
        float4 v = {acc[i][j][0] + bb.x, acc[i][j][1] + bb.y,
                    acc[i][j][2] + bb.z, acc[i][j][3] + bb.w};
        *(float4*)&Out[rb + j * 16] = v;
      }
    }
  } else {  // EPI == 2: only n<32 carries data
    if (wn == 0) {
#pragma unroll
      for (int i = 0; i < 4; i++) {
        const int m = bm * 128 + m0 + i * 16;
        const int i0 = tki[m * 2], i1 = tki[m * 2 + 1];
        const float p0 = tkp[m * 2], p1 = tkp[m * 2 + 1];
#pragma unroll
        for (int j = 0; j < 2; j++) {
          const int nb = n0 + j * 16;  // 0..28, one expert block per quad
          const int e = nb >> 3;
          const float wgt = (i0 == e ? p0 : 0.0f) + (i1 == e ? p1 : 0.0f);
          f16x4 o = {(f16)(wgt * gelu_exact(acc[i][j][0])),
                     (f16)(wgt * gelu_exact(acc[i][j][1])),
                     (f16)(wgt * gelu_exact(acc[i][j][2])),
                     (f16)(wgt * gelu_exact(acc[i][j][3]))};
          *(f16x4*)&Hout[(size_t)m * 32 + nb] = o;
        }
      }
    }
  }
}

extern "C" void kernel_launch(void* const* d_in, const int* in_sizes, int n_in,
                              void* d_out, int out_size, void* d_ws,
                              size_t ws_size, hipStream_t stream) {
  const float* x = (const float*)d_in[0];
  const float* W1 = (const float*)d_in[1];
  const float* b1 = (const float*)d_in[2];
  const float* W2 = (const float*)d_in[3];
  const float* b2 = (const float*)d_in[4];
  const float* wd = (const float*)d_in[5];
  const float* wu = (const float*)d_in[6];
  // d_in[7] = gate_probs (unused; topk already provided)
  const float* tkp = (const float*)d_in[8];
  const int* tki = (const int*)d_in[9];
  float* out = (float*)d_out;

  const int T = in_sizes[0] / TD;  // 50176

  // workspace layout
  char* p = (char*)d_ws;
  f16* W1T = (f16*)p; p += (size_t)TDH * TD * sizeof(f16);  // [2048][512]
  f16* W2T = (f16*)p; p += (size_t)TD * TDH * sizeof(f16);  // [512][2048]
  f16* wdT = (f16*)p; p += (size_t)128 * TD * sizeof(f16);  // [128][512]
  f16* wuT = (f16*)p; p += (size_t)TD * 32 * sizeof(f16);   // [512][32]
  size_t fixed = (size_t)(p - (char*)d_ws);
  const size_t per_tok = (size_t)(TD + TDH + 32) * sizeof(f16);  // 5184 B
  long mc = (long)((ws_size > fixed ? ws_size - fixed : 0) / per_tok);
  if (mc > T) mc = T;
  mc = (mc / 128) * 128;
  if (mc < 128) mc = 128;  // minimum viable chunk
  f16* xb = (f16*)p; p += (size_t)mc * TD * sizeof(f16);
  f16* Hb = (f16*)p; p += (size_t)mc * TDH * sizeof(f16);
  f16* gb = (f16*)p;

  // weight conversion/transpose (tiled, both sides coalesced)
  k_trans<<<dim3(TDH / 32, TD / 32), dim3(32, 8), 0, stream>>>(W1T, W1, TD, TDH);
  k_trans<<<dim3(TD / 32, TDH / 32), dim3(32, 8), 0, stream>>>(W2T, W2, TDH, TD);
  k_wdT<<<dim3(65536 / 256), 256, 0, stream>>>(wdT, wd);
  k_wuT<<<dim3(16384 / 256), 256, 0, stream>>>(wuT, wu);

  for (long off = 0; off < T; off += mc) {
    long m = T - off;
    if (m > mc) m = mc;
    const int mt = (int)(m / 128);
    const int n4 = (int)(m * TD / 4);
    k_conv_x<<<dim3((n4 + 255) / 256), 256, 0, stream>>>(xb, x + off * TD, n4);
    // g[m][32] = topk-weighted gelu(x @ wd^T)   (K=512, N=128 padded)
    k_gemm<2><<<dim3(mt, 1), 256, 0, stream>>>(xb, wdT, TD, TD, TD, nullptr,
                                               gb, 32, nullptr, 0,
                                               tkp + off * 2, tki + off * 2,
                                               nullptr, nullptr);
    // H = gelu(x @ W1^T + b1)   (K=512, N=2048)
    k_gemm<0><<<dim3(mt, TDH / 128), 256, 0, stream>>>(
        xb, W1T, TD, TD, TD, b1, Hb, TDH, nullptr, 0, nullptr, nullptr,
        nullptr, nullptr);
    // out = H @ W2^T + g @ wu^T + b2   (K=2048 main + fused K=32 LoRA step)
    k_gemm<1><<<dim3(mt, TD / 128), 256, 0, stream>>>(
        Hb, W2T, TDH, TDH, TDH, b2, nullptr, 0, out + off * TD, TD, nullptr,
        nullptr, gb, wuT);
  }
}

// Round 4
// 564.832 us; speedup vs baseline: 1.3603x; 1.0833x over previous
//
#include <hip/hip_runtime.h>

typedef _Float16 f16;
typedef _Float16 f16x8 __attribute__((ext_vector_type(8)));
typedef _Float16 f16x4 __attribute__((ext_vector_type(4)));
typedef float f32x4 __attribute__((ext_vector_type(4)));

#define TD 512
#define TDH 2048

// tanh-form GELU: x * sigmoid(1.595769122*x + 0.0713548162*x^3)
// ~8 VALU inst (v_exp_f32 + v_rcp_f32) vs ~35 for erff. |err| vs exact ~3e-4.
__device__ __forceinline__ float gelu_fast(float x) {
  float u = x * fmaf(x * x, 0.0713548162f, 1.595769122f);
  float e = __expf(-u);
  return x * __builtin_amdgcn_rcpf(1.0f + e);
}

__device__ __forceinline__ void glds16(const f16* g, f16* l) {
  __builtin_amdgcn_global_load_lds(
      (const __attribute__((address_space(1))) void*)g,
      (__attribute__((address_space(3))) void*)l, 16, 0, 0);
}

__global__ __launch_bounds__(256) void k_conv_x(f16* __restrict__ dst,
                                                const float* __restrict__ src,
                                                int n4) {
  int i = blockIdx.x * 256 + threadIdx.x;
  if (i >= n4) return;
  float4 v = ((const float4*)src)[i];
  f16x4 o = {(f16)v.x, (f16)v.y, (f16)v.z, (f16)v.w};
  ((f16x4*)dst)[i] = o;
}

// Tiled transpose: dst[c*R + r] = src[r*C + c], both sides coalesced.
// grid (C/32, R/32), block (32, 8).
__global__ void k_trans(f16* __restrict__ dst, const float* __restrict__ src,
                        int R, int C) {
  __shared__ float t[32][33];
  const int bx = blockIdx.x, by = blockIdx.y;
  const int tx = threadIdx.x, ty = threadIdx.y;
#pragma unroll
  for (int s = 0; s < 32; s += 8)
    t[ty + s][tx] = src[(size_t)(by * 32 + ty + s) * C + bx * 32 + tx];
  __syncthreads();
#pragma unroll
  for (int s = 0; s < 32; s += 8)
    dst[(size_t)(bx * 32 + ty + s) * R + by * 32 + tx] = (f16)t[tx][ty + s];
}

// wdT[128][512]: n=e*8+r for n<24 else 0 ; src wd[3][512][8]
__global__ __launch_bounds__(256) void k_wdT(f16* __restrict__ dst,
                                             const float* __restrict__ wd) {
  int i = blockIdx.x * 256 + threadIdx.x;  // 65536 total
  int n = i >> 9, k = i & 511;
  float v = (n < 24) ? wd[(size_t)((n >> 3) * 512 + k) * 8 + (n & 7)] : 0.0f;
  dst[i] = (f16)v;
}

// wuT[512][32]: wuT[d][e*8+r] = wu[e][r][d] for er<24 else 0 ; src wu[3][8][512]
__global__ __launch_bounds__(256) void k_wuT(f16* __restrict__ dst,
                                             const float* __restrict__ wu) {
  int i = blockIdx.x * 256 + threadIdx.x;  // 16384 total
  int d = i >> 5, er = i & 31;
  float v = (er < 24) ? wu[(size_t)(er >> 3) * 4096 + (er & 7) * 512 + d] : 0.0f;
  dst[i] = (f16)v;
}

// 128x128 tile, BK=32, 4 waves (2x2), double-buffered LDS, early-issue STAGE.
// A: [M][K] K-contig. B: B^T layout [N][K] K-contig.
// LDS slot swizzle (conflict-free): LDS[row][s] = glob[row][s ^ ((row>>1)&3)]
//   -> bank-quad = (4*row + s')%8 covers all 8 quads per 8 rows (2 lanes/quad).
// MFMA called as mfma(bf, af) so D reg axis = N (4 consecutive cols/thread).
// EPI 0: Hout[m][n] = f16(gelu(acc + bias[n]))
// EPI 1: Out[m][n]  = acc(main K  PLUS one fused K=32 step Ag@Bg) + bias[n]
// EPI 2: Hout[m*32+n] = f16(topk_w(m, n>>3) * gelu(acc)), n<32
template <int EPI>
__global__ __launch_bounds__(256) void k_gemm(
    const f16* __restrict__ A, const f16* __restrict__ B, int Kt, int lda,
    int ldb, const float* __restrict__ bias, f16* __restrict__ Hout, int ldh,
    float* __restrict__ Out, int ldc, const float* __restrict__ tkp,
    const int* __restrict__ tki, const f16* __restrict__ Ag,
    const f16* __restrict__ Bg) {
  __shared__ __align__(16) f16 As[2][128 * 32];
  __shared__ __align__(16) f16 Bs[2][128 * 32];
  const int tid = threadIdx.x;
  const int lane = tid & 63;
  const int w = tid >> 6;
  const int wm = w >> 1, wn = w & 1;
  const int bm = blockIdx.x, bn = blockIdx.y;

  // Staging: wave w fills chunks 2w,2w+1 (16 rows x 64B each). LDS dest is
  // wave-linear (lane l -> row c*16+l/4, 16B slot l&3). Source slot is
  // XOR-swizzled with ((row>>1)&3) - both-sides involution (m173).
  const int c0 = 2 * w;
  const int lrow = lane >> 2;
  const int srow = c0 * 16 + lrow;
  const int skk = ((lane & 3) ^ ((lrow >> 1) & 3)) * 8;
  const f16* gA = A + (size_t)(bm * 128 + srow) * lda + skk;
  const f16* gB = B + (size_t)(bn * 128 + srow) * ldb + skk;
  f16* lA0 = &As[0][c0 * 512];
  f16* lA1 = &As[1][c0 * 512];
  f16* lB0 = &Bs[0][c0 * 512];
  f16* lB1 = &Bs[1][c0 * 512];

  f32x4 acc[4][4] = {};

  const int frow = lane & 15;
  // read-side swizzle: slot' = (lane>>4) ^ ((row>>1)&3); row==frow mod 16
  const int swk = (((lane >> 4) ^ ((frow >> 1) & 3))) * 8;

  const int nt = Kt / 32;

  // prologue: stage k=0 into buf0
  glds16(gA, lA0);
  glds16(gA + (size_t)16 * lda, lA0 + 512);
  glds16(gB, lB0);
  glds16(gB + (size_t)16 * ldb, lB0 + 512);
  __syncthreads();

  for (int t = 0; t < nt; ++t) {
    // issue next-tile stage FIRST (loads fly under ds_read + MFMA)
    f16* dA = (t & 1) ? lA0 : lA1;
    f16* dB = (t & 1) ? lB0 : lB1;
    if (t + 1 < nt) {
      const int k = (t + 1) * 32;
      glds16(gA + k, dA);
      glds16(gA + k + (size_t)16 * lda, dA + 512);
      glds16(gB + k, dB);
      glds16(gB + k + (size_t)16 * ldb, dB + 512);
    } else if (EPI == 1) {  // fused LoRA-up step: A=Ag[m][32], B=Bg[n][32]
      const f16* gAg = Ag + (size_t)(bm * 128 + srow) * 32 + skk;
      const f16* gBg = Bg + (size_t)(bn * 128 + srow) * 32 + skk;
      glds16(gAg, dA);
      glds16(gAg + 512, dA + 512);
      glds16(gBg, dB);
      glds16(gBg + 512, dB + 512);
    }
    const f16* rA = As[t & 1];
    const f16* rB = Bs[t & 1];
    f16x8 af[4], bf[4];
#pragma unroll
    for (int i = 0; i < 4; i++)
      af[i] = *(const f16x8*)&rA[(wm * 64 + i * 16 + frow) * 32 + swk];
#pragma unroll
    for (int j = 0; j < 4; j++)
      bf[j] = *(const f16x8*)&rB[(wn * 64 + j * 16 + frow) * 32 + swk];
#pragma unroll
    for (int i = 0; i < 4; i++)
#pragma unroll
      for (int j = 0; j < 4; j++)
        acc[i][j] = __builtin_amdgcn_mfma_f32_16x16x32_f16(bf[j], af[i],
                                                           acc[i][j], 0, 0, 0);
    __syncthreads();  // vmcnt(0): next buf staged; lgkm: reads done before overwrite
  }

  if constexpr (EPI == 1) {  // consume the fused g @ wuT tile
    const f16* rA = As[nt & 1];
    const f16* rB = Bs[nt & 1];
    f16x8 af[4], bf[4];
#pragma unroll
    for (int i = 0; i < 4; i++)
      af[i] = *(const f16x8*)&rA[(wm * 64 + i * 16 + frow) * 32 + swk];
#pragma unroll
    for (int j = 0; j < 4; j++)
      bf[j] = *(const f16x8*)&rB[(wn * 64 + j * 16 + frow) * 32 + swk];
#pragma unroll
    for (int i = 0; i < 4; i++)
#pragma unroll
      for (int j = 0; j < 4; j++)
        acc[i][j] = __builtin_amdgcn_mfma_f32_16x16x32_f16(bf[j], af[i],
                                                           acc[i][j], 0, 0, 0);
  }

  // D layout with swapped operands: col(lane&15) -> m, reg axis -> n.
  // m = wm*64 + i*16 + (lane&15); n = wn*64 + j*16 + (lane>>4)*4 + r
  const int m0 = wm * 64 + (lane & 15);
  const int n0 = wn * 64 + ((lane >> 4) << 2);

  if constexpr (EPI == 0) {
#pragma unroll
    for (int i = 0; i < 4; i++) {
      const size_t rb = (size_t)(bm * 128 + m0 + i * 16) * ldh + bn * 128 + n0;
#pragma unroll
      for (int j = 0; j < 4; j++) {
        const float4 bb = *(const float4*)&bias[bn * 128 + n0 + j * 16];
        f16x4 o = {(f16)gelu_fast(acc[i][j][0] + bb.x),
                   (f16)gelu_fast(acc[i][j][1] + bb.y),
                   (f16)gelu_fast(acc[i][j][2] + bb.z),
                   (f16)gelu_fast(acc[i][j][3] + bb.w)};
        *(f16x4*)&Hout[rb + j * 16] = o;
      }
    }
  } else if constexpr (EPI == 1) {
#pragma unroll
    for (int i = 0; i < 4; i++) {
      const size_t rb = (size_t)(bm * 128 + m0 + i * 16) * ldc + bn * 128 + n0;
#pragma unroll
      for (int j = 0; j < 4; j++) {
        const float4 bb = *(const float4*)&bias[bn * 128 + n0 + j * 16];
        float4 v = {acc[i][j][0] + bb.x, acc[i][j][1] + bb.y,
                    acc[i][j][2] + bb.z, acc[i][j][3] + bb.w};
        *(float4*)&Out[rb + j * 16] = v;
      }
    }
  } else {  // EPI == 2: only n<32 carries data
    if (wn == 0) {
#pragma unroll
      for (int i = 0; i < 4; i++) {
        const int m = bm * 128 + m0 + i * 16;
        const int i0 = tki[m * 2], i1 = tki[m * 2 + 1];
        const float p0 = tkp[m * 2], p1 = tkp[m * 2 + 1];
#pragma unroll
        for (int j = 0; j < 2; j++) {
          const int nb = n0 + j * 16;  // 0..28, one expert block per quad
          const int e = nb >> 3;
          const float wgt = (i0 == e ? p0 : 0.0f) + (i1 == e ? p1 : 0.0f);
          f16x4 o = {(f16)(wgt * gelu_fast(acc[i][j][0])),
                     (f16)(wgt * gelu_fast(acc[i][j][1])),
                     (f16)(wgt * gelu_fast(acc[i][j][2])),
                     (f16)(wgt * gelu_fast(acc[i][j][3]))};
          *(f16x4*)&Hout[(size_t)m * 32 + nb] = o;
        }
      }
    }
  }
}

extern "C" void kernel_launch(void* const* d_in, const int* in_sizes, int n_in,
                              void* d_out, int out_size, void* d_ws,
                              size_t ws_size, hipStream_t stream) {
  const float* x = (const float*)d_in[0];
  const float* W1 = (const float*)d_in[1];
  const float* b1 = (const float*)d_in[2];
  const float* W2 = (const float*)d_in[3];
  const float* b2 = (const float*)d_in[4];
  const float* wd = (const float*)d_in[5];
  const float* wu = (const float*)d_in[6];
  // d_in[7] = gate_probs (unused; topk already provided)
  const float* tkp = (const float*)d_in[8];
  const int* tki = (const int*)d_in[9];
  float* out = (float*)d_out;

  const int T = in_sizes[0] / TD;  // 50176

  // workspace layout
  char* p = (char*)d_ws;
  f16* W1T = (f16*)p; p += (size_t)TDH * TD * sizeof(f16);  // [2048][512]
  f16* W2T = (f16*)p; p += (size_t)TD * TDH * sizeof(f16);  // [512][2048]
  f16* wdT = (f16*)p; p += (size_t)128 * TD * sizeof(f16);  // [128][512]
  f16* wuT = (f16*)p; p += (size_t)TD * 32 * sizeof(f16);   // [512][32]
  size_t fixed = (size_t)(p - (char*)d_ws);
  const size_t per_tok = (size_t)(TD + TDH + 32) * sizeof(f16);  // 5184 B
  long mc = (long)((ws_size > fixed ? ws_size - fixed : 0) / per_tok);
  if (mc > T) mc = T;
  mc = (mc / 128) * 128;
  if (mc < 128) mc = 128;  // minimum viable chunk
  f16* xb = (f16*)p; p += (size_t)mc * TD * sizeof(f16);
  f16* Hb = (f16*)p; p += (size_t)mc * TDH * sizeof(f16);
  f16* gb = (f16*)p;

  // weight conversion/transpose (tiled, both sides coalesced)
  k_trans<<<dim3(TDH / 32, TD / 32), dim3(32, 8), 0, stream>>>(W1T, W1, TD, TDH);
  k_trans<<<dim3(TD / 32, TDH / 32), dim3(32, 8), 0, stream>>>(W2T, W2, TDH, TD);
  k_wdT<<<dim3(65536 / 256), 256, 0, stream>>>(wdT, wd);
  k_wuT<<<dim3(16384 / 256), 256, 0, stream>>>(wuT, wu);

  for (long off = 0; off < T; off += mc) {
    long m = T - off;
    if (m > mc) m = mc;
    const int mt = (int)(m / 128);
    const int n4 = (int)(m * TD / 4);
    k_conv_x<<<dim3((n4 + 255) / 256), 256, 0, stream>>>(xb, x + off * TD, n4);
    // g[m][32] = topk-weighted gelu(x @ wd^T)   (K=512, N=128 padded)
    k_gemm<2><<<dim3(mt, 1), 256, 0, stream>>>(xb, wdT, TD, TD, TD, nullptr,
                                               gb, 32, nullptr, 0,
                                               tkp + off * 2, tki + off * 2,
                                               nullptr, nullptr);
    // H = gelu(x @ W1^T + b1)   (K=512, N=2048)
    k_gemm<0><<<dim3(mt, TDH / 128), 256, 0, stream>>>(
        xb, W1T, TD, TD, TD, b1, Hb, TDH, nullptr, 0, nullptr, nullptr,
        nullptr, nullptr);
    // out = H @ W2^T + g @ wu^T + b2   (K=2048 main + fused K=32 LoRA step)
    k_gemm<1><<<dim3(mt, TD / 128), 256, 0, stream>>>(
        Hb, W2T, TDH, TDH, TDH, b2, nullptr, 0, out + off * TD, TD, nullptr,
        nullptr, gb, wuT);
  }
}